// Round 1
// baseline (988.180 us; speedup 1.0000x reference)
//
#include <hip/hip_runtime.h>

// AdaptiveEdgeSparsifier: per-row (n=4096) exact top-k threshold (k=2867),
// keep >= kth largest, zero the rest.
//
// v2: one WAVE per row. All 4096 row elements live in registers
// (64 x u32 per lane). Exact 32-bit threshold found by MSB-first bisection
// with ballot+popcount counting: no LDS, no atomics, no barriers.
// Previous version's 256-bin LDS-atomic histogram serialized badly because
// N(0,1) exponents concentrate the top-8-bit digit into <10 hot buckets.

#define NCOL 4096
#define KSEL 2867   // k = max(1, int(4096 * (1.0 - 0.3))) = 2867

__global__ __launch_bounds__(256, 4) void sparsify_kernel(const float* __restrict__ adj,
                                                          float* __restrict__ out,
                                                          int nrows) {
    const int lane = threadIdx.x & 63;
    const int wave = threadIdx.x >> 6;
    const int row  = blockIdx.x * 4 + wave;
    if (row >= nrows) return;   // wave-uniform guard

    const float4* __restrict__ in4  = (const float4*)(adj + (size_t)row * NCOL);
    float4* __restrict__       out4 = (float4*)(out + (size_t)row * NCOL);

    // Load 64 elements/lane, coalesced float4 (lane-contiguous 1 KiB per instr),
    // and map to order-preserving uint space:
    //   positives: bits | 0x80000000 ; negatives: ~bits  (strictly monotone)
    unsigned u[64];
#pragma unroll
    for (int c = 0; c < 16; ++c) {
        const float4 v = in4[lane + 64 * c];
        const unsigned bx = __float_as_uint(v.x);
        const unsigned by = __float_as_uint(v.y);
        const unsigned bz = __float_as_uint(v.z);
        const unsigned bw = __float_as_uint(v.w);
        u[4 * c + 0] = bx ^ ((unsigned)((int)bx >> 31) | 0x80000000u);
        u[4 * c + 1] = by ^ ((unsigned)((int)by >> 31) | 0x80000000u);
        u[4 * c + 2] = bz ^ ((unsigned)((int)bz >> 31) | 0x80000000u);
        u[4 * c + 3] = bw ^ ((unsigned)((int)bw >> 31) | 0x80000000u);
    }

    // 32-step bisection for the exact kth-largest value in u-space:
    // T = max{ t : count(u >= t) >= k }.  Per step: 64 v_cmp (VALU) +
    // 64 s_bcnt1/s_add (SALU, co-issued). cand/cnt are wave-uniform -> SGPR.
    unsigned cand = 0u;
#pragma unroll 1   // keep outer loop rolled: ~1 KiB body, I$-friendly
    for (int b = 31; b >= 0; --b) {
        const unsigned c2 = cand | (1u << b);
        unsigned cnt = 0u;
#pragma unroll
        for (int i = 0; i < 64; ++i)
            cnt += (unsigned)__popcll(__ballot(u[i] >= c2));
        if (cnt >= KSEL) cand = c2;
    }

    // Inverse map -> float threshold; compare in FLOAT space so ±0 ties
    // behave exactly like the reference's (adj >= kth_val).
    const unsigned tb = (cand & 0x80000000u) ? (cand ^ 0x80000000u) : ~cand;
    const float thr = __uint_as_float(tb);

#pragma unroll
    for (int c = 0; c < 16; ++c) {
        float f[4];
#pragma unroll
        for (int j = 0; j < 4; ++j) {
            const unsigned uu = u[4 * c + j];
            const unsigned bb = (uu & 0x80000000u) ? (uu ^ 0x80000000u) : ~uu;
            f[j] = __uint_as_float(bb);   // bit-exact round trip of the input
        }
        float4 o;
        o.x = (f[0] >= thr) ? f[0] : 0.0f;
        o.y = (f[1] >= thr) ? f[1] : 0.0f;
        o.z = (f[2] >= thr) ? f[2] : 0.0f;
        o.w = (f[3] >= thr) ? f[3] : 0.0f;
        out4[lane + 64 * c] = o;
    }
}

extern "C" void kernel_launch(void* const* d_in, const int* in_sizes, int n_in,
                              void* d_out, int out_size, void* d_ws, size_t ws_size,
                              hipStream_t stream) {
    const float* adj = (const float*)d_in[0];
    float* out = (float*)d_out;
    const int rows = in_sizes[0] / NCOL;       // 8 * 4096 = 32768
    const int blocks = (rows + 3) / 4;         // 4 waves (rows) per 256-thread block
    sparsify_kernel<<<blocks, 256, 0, stream>>>(adj, out, rows);
}

// Round 2
// 912.769 us; speedup vs baseline: 1.0826x; 1.0826x over previous
//
#include <hip/hip_runtime.h>

// AdaptiveEdgeSparsifier: per-row (n=4096) exact top-k threshold (k=2867),
// keep >= kth largest, zero the rest.
//
// v3: one WAVE per row, all 4096 elements resident in registers (64 u32/lane).
// Fixes vs v2 (which regressed to 389us/dispatch):
//  - VGPR_Count=56 proved the compiler REMATERIALIZED u[] (re-load + re-map
//    from global every bisection step, ~16K VALU cyc/row). asm-pin each u[i]
//    so it must stay in a VGPR (asm output can't be recomputed).
//  - ballot+popcll put 2 SALU/elem on the shared scalar unit; replaced with
//    per-lane VALU count (v_cmp+v_addc, 2 VALU/elem) + one 6-step shfl_xor
//    wave-reduce per bisection step (off the scalar pipe).

#define NCOL 4096
#define KSEL 2867   // k = max(1, int(4096 * (1.0 - 0.3))) = 2867

__global__ __launch_bounds__(256, 4) void sparsify_kernel(const float* __restrict__ adj,
                                                          float* __restrict__ out,
                                                          int nrows) {
    const int lane = threadIdx.x & 63;
    const int wave = threadIdx.x >> 6;
    const int row  = blockIdx.x * 4 + wave;
    if (row >= nrows) return;   // wave-uniform guard

    const float4* __restrict__ in4  = (const float4*)(adj + (size_t)row * NCOL);
    float4* __restrict__       out4 = (float4*)(out + (size_t)row * NCOL);

    // Load 64 elements/lane (coalesced float4) and map to order-preserving
    // uint space: positives -> bits|0x80000000, negatives -> ~bits.
    unsigned u[64];
#pragma unroll
    for (int c = 0; c < 16; ++c) {
        const float4 v = in4[lane + 64 * c];
        const unsigned bx = __float_as_uint(v.x);
        const unsigned by = __float_as_uint(v.y);
        const unsigned bz = __float_as_uint(v.z);
        const unsigned bw = __float_as_uint(v.w);
        u[4 * c + 0] = bx ^ ((unsigned)((int)bx >> 31) | 0x80000000u);
        u[4 * c + 1] = by ^ ((unsigned)((int)by >> 31) | 0x80000000u);
        u[4 * c + 2] = bz ^ ((unsigned)((int)bz >> 31) | 0x80000000u);
        u[4 * c + 3] = bw ^ ((unsigned)((int)bw >> 31) | 0x80000000u);
    }

    // Pin: force each mapped value into a VGPR. An asm-defined value cannot
    // be rematerialized from the global load, so u[] stays resident across
    // the bisection loop (needs ~100 VGPR, fits the 128 cap of (256,4)).
#pragma unroll
    for (int i = 0; i < 64; ++i) asm volatile("" : "+v"(u[i]));

    // 32-step MSB-first bisection for the exact kth-largest in u-space:
    // cand = max{ t : count(u >= t) >= k }. Per step: 64x(v_cmp+v_addc)
    // per-lane count, then a 6-level shfl_xor reduce (uniform result).
    unsigned cand = 0u;
#pragma unroll 1   // keep outer loop rolled (I$-friendly)
    for (int b = 31; b >= 0; --b) {
        const unsigned c2 = cand | (1u << b);
        unsigned cnt = 0u;
#pragma unroll
        for (int i = 0; i < 64; ++i)
            cnt += (unsigned)(u[i] >= c2);
#pragma unroll
        for (int d = 1; d < 64; d <<= 1)
            cnt += __shfl_xor(cnt, d, 64);
        if (cnt >= KSEL) cand = c2;   // wave-uniform update
    }

    // Output: select in u-space (total order; ±0 mismatches vs float '>='
    // still produce a zero value -> identical output), reconstruct the
    // original float bits by the inverse order-preserving map.
#pragma unroll
    for (int c = 0; c < 16; ++c) {
        float f[4];
        unsigned keepm[4];
#pragma unroll
        for (int j = 0; j < 4; ++j) {
            const unsigned uu = u[4 * c + j];
            const unsigned s  = (unsigned)((int)uu >> 31);            // 0xFFFF.. if mapped-from-positive
            const unsigned bb = uu ^ ((~s) | 0x80000000u);            // inverse map (bit-exact)
            f[j] = __uint_as_float(bb);
            keepm[j] = (uu >= cand);
        }
        float4 o;
        o.x = keepm[0] ? f[0] : 0.0f;
        o.y = keepm[1] ? f[1] : 0.0f;
        o.z = keepm[2] ? f[2] : 0.0f;
        o.w = keepm[3] ? f[3] : 0.0f;
        out4[lane + 64 * c] = o;
    }
}

extern "C" void kernel_launch(void* const* d_in, const int* in_sizes, int n_in,
                              void* d_out, int out_size, void* d_ws, size_t ws_size,
                              hipStream_t stream) {
    const float* adj = (const float*)d_in[0];
    float* out = (float*)d_out;
    const int rows = in_sizes[0] / NCOL;       // 8 * 4096 = 32768
    const int blocks = (rows + 3) / 4;         // 4 waves (rows) per 256-thread block
    sparsify_kernel<<<blocks, 256, 0, stream>>>(adj, out, rows);
}

// Round 3
// 908.817 us; speedup vs baseline: 1.0873x; 1.0043x over previous
//
#include <hip/hip_runtime.h>

// AdaptiveEdgeSparsifier: per-row (n=4096) exact top-k threshold (k=2867),
// keep >= kth largest, zero the rest.
//
// v4: one WAVE per row, all 4096 elements resident in registers (64 u32/lane,
// asm-pinned against rematerialization — v2's VGPR=56 proved LLVM re-loads
// otherwise). Counting per bisection step via ballot+popcount:
//   per element: 1 VALU (v_cmp into SGPR pair) + 2 SALU (s_bcnt1_b64 + s_add),
// SALU co-issues with VALU and the count lands wave-uniform in an SGPR —
// no cross-lane shuffle reduce (v3 paid 6 dependent ds_bpermute per step,
// ~240 cyc serial latency x 32 steps). Nontemporal loads/stores: both
// streams are touch-once, keep them out of L2/LLC.

#define NCOL 4096
#define KSEL 2867   // k = max(1, int(4096 * (1.0 - 0.3))) = 2867

typedef float vf4 __attribute__((ext_vector_type(4)));

__global__ __launch_bounds__(256, 4) void sparsify_kernel(const float* __restrict__ adj,
                                                          float* __restrict__ out,
                                                          int nrows) {
    const int lane = threadIdx.x & 63;
    const int wave = threadIdx.x >> 6;
    const int row  = blockIdx.x * 4 + wave;
    if (row >= nrows) return;   // wave-uniform guard

    const vf4* __restrict__ in4  = (const vf4*)(adj + (size_t)row * NCOL);
    vf4* __restrict__       out4 = (vf4*)(out + (size_t)row * NCOL);

    // Load 64 elements/lane (coalesced 16B/lane) and map to order-preserving
    // uint space: positives -> bits|0x80000000, negatives -> ~bits.
    unsigned u[64];
#pragma unroll
    for (int c = 0; c < 16; ++c) {
        const vf4 v = __builtin_nontemporal_load(in4 + lane + 64 * c);
#pragma unroll
        for (int j = 0; j < 4; ++j) {
            const unsigned b = __float_as_uint(v[j]);
            u[4 * c + j] = b ^ ((unsigned)((int)b >> 31) | 0x80000000u);
        }
    }

    // Pin: asm-defined values cannot be rematerialized from the global load,
    // so u[] must stay in VGPRs across the bisection (~100 VGPR, fits the
    // 128-VGPR cap of __launch_bounds__(256,4)).
#pragma unroll
    for (int i = 0; i < 64; ++i) asm volatile("" : "+v"(u[i]));

    // 32-step MSB-first bisection for the exact kth-largest in u-space:
    // cand = max{ t : count(u >= t) >= k }.
    // Per step: 64 v_cmp (VALU, 2cyc) + 64 x (s_bcnt1_b64 + s_add) on the
    // co-issued scalar pipe; count is wave-uniform, no shuffle reduce.
    unsigned cand = 0u;
#pragma unroll 1   // keep outer loop rolled (I$-friendly, serial anyway)
    for (int b = 31; b >= 0; --b) {
        const unsigned c2 = cand | (1u << b);
        unsigned cnt = 0u;
#pragma unroll
        for (int i = 0; i < 64; ++i)
            cnt += (unsigned)__popcll(__ballot(u[i] >= c2));
        if (cnt >= KSEL) cand = c2;   // wave-uniform update
    }

    // Output: select in u-space (total order; ±0 mismatch vs float '>='
    // still yields a zero value -> identical output), reconstruct float
    // bits by the inverse order-preserving map.
#pragma unroll
    for (int c = 0; c < 16; ++c) {
        vf4 o;
#pragma unroll
        for (int j = 0; j < 4; ++j) {
            const unsigned uu = u[4 * c + j];
            const unsigned s  = (unsigned)((int)uu >> 31);   // ones if mapped-from-positive
            const unsigned bb = uu ^ ((~s) | 0x80000000u);   // inverse map (bit-exact)
            const float    f  = __uint_as_float(bb);
            o[j] = (uu >= cand) ? f : 0.0f;
        }
        __builtin_nontemporal_store(o, out4 + lane + 64 * c);
    }
}

extern "C" void kernel_launch(void* const* d_in, const int* in_sizes, int n_in,
                              void* d_out, int out_size, void* d_ws, size_t ws_size,
                              hipStream_t stream) {
    const float* adj = (const float*)d_in[0];
    float* out = (float*)d_out;
    const int rows = in_sizes[0] / NCOL;       // 8 * 4096 = 32768
    const int blocks = (rows + 3) / 4;         // 4 waves (rows) per 256-thread block
    sparsify_kernel<<<blocks, 256, 0, stream>>>(adj, out, rows);
}

// Round 4
// 823.287 us; speedup vs baseline: 1.2003x; 1.1039x over previous
//
#include <hip/hip_runtime.h>

// AdaptiveEdgeSparsifier: per-row (n=4096) exact top-k threshold (k=2867),
// keep >= kth largest, zero the rest.
//
// v5: wave-per-row, register-resident, BIT-PLANE bisection.
//  - v3 lesson: cmp+addc count -> VCC-serialized dependent chain (~8cyc/elem,
//    16K cyc/row). v4 lesson: ballot+s_bcnt1 -> 4096 SALU/row = 218us on the
//    per-CU scalar unit. Both ~310us. Count must leave both narrow pipes.
//  - Here: two in-register 32x32 bit-matrix transposes turn 64 values/lane
//    into 64 bit-planes/lane. A bisection step then counts ALL 64 elements
//    with 2x v_and + 2x v_bcnt (~5 VALU), reduced across lanes with a 6-op
//    DPP sequence (row_shr 1/2/4/8 + row_bcast 15/31) -- pure VALU, no DS,
//    no SALU pressure, no carry chains. 32 steps ~= 500 VALU instr/row.
//  - Transpose is an involution: run it again after bisection to recover the
//    values for the select/store pass. j=16/8 stages use v_perm_b32 (2 ops
//    per pair instead of 6). Everything fully unrolled => static reg indices.

#define NCOL 4096
#define KSEL 2867   // k = max(1, int(4096 * (1.0 - 0.3))) = 2867

typedef float vf4 __attribute__((ext_vector_type(4)));

#define DPPU(old, src, ctrl, rm, bm, bc) \
    __builtin_amdgcn_update_dpp(old, src, ctrl, rm, bm, bc)

// Full wave64 sum; returns total (broadcast from lane 63 via readlane).
__device__ __forceinline__ unsigned wave_sum(unsigned x) {
    int v = (int)x;
    v += DPPU(0, v, 0x111, 0xf, 0xf, true);   // row_shr:1
    v += DPPU(0, v, 0x112, 0xf, 0xf, true);   // row_shr:2
    v += DPPU(0, v, 0x114, 0xf, 0xf, true);   // row_shr:4
    v += DPPU(0, v, 0x118, 0xf, 0xf, true);   // row_shr:8  -> lane15 of each row = row sum
    v += DPPU(0, v, 0x142, 0xa, 0xf, true);   // row_bcast:15 -> rows 1,3
    v += DPPU(0, v, 0x143, 0xc, 0xf, true);   // row_bcast:31 -> rows 2,3; lane63 = total
    return (unsigned)__builtin_amdgcn_readlane(v, 63);
}

// 32x32 bit-matrix transpose stages (Hacker's Delight 7-3, in place).
// After transpose32(A): bit b of original element i sits in A[31-b], bit (31-i).
template <int J, unsigned M>
__device__ __forceinline__ void tstage_xor(unsigned* A) {
#pragma unroll
    for (int k = 0; k < 32; ++k)
        if ((k & J) == 0) {
            const unsigned t = (A[k] ^ (A[k + J] >> J)) & M;
            A[k] ^= t;
            A[k + J] ^= t << J;
        }
}

__device__ __forceinline__ void tstage16(unsigned* A) {   // j=16 via byte perm
#pragma unroll
    for (int k = 0; k < 16; ++k) {
        const unsigned a = A[k], b = A[k + 16];
        A[k]      = __builtin_amdgcn_perm(a, b, 0x07060302u); // [a.b3,a.b2,b.b3,b.b2]
        A[k + 16] = __builtin_amdgcn_perm(a, b, 0x05040100u); // [a.b1,a.b0,b.b1,b.b0]
    }
}

__device__ __forceinline__ void tstage8(unsigned* A) {    // j=8 via byte perm
#pragma unroll
    for (int k = 0; k < 32; ++k)
        if ((k & 8) == 0) {
            const unsigned a = A[k], b = A[k + 8];
            A[k]     = __builtin_amdgcn_perm(a, b, 0x07030501u); // [a.b3,b.b3,a.b1,b.b1]
            A[k + 8] = __builtin_amdgcn_perm(a, b, 0x06020400u); // [a.b2,b.b2,a.b0,b.b0]
        }
}

__device__ __forceinline__ void transpose32(unsigned* A) {
    tstage16(A);
    tstage8(A);
    tstage_xor<4, 0x0F0F0F0Fu>(A);
    tstage_xor<2, 0x33333333u>(A);
    tstage_xor<1, 0x55555555u>(A);
}

__global__ __launch_bounds__(256, 4) void sparsify_kernel(const float* __restrict__ adj,
                                                          float* __restrict__ out,
                                                          int nrows) {
    const int lane = threadIdx.x & 63;
    const int wave = threadIdx.x >> 6;
    const int row  = blockIdx.x * 4 + wave;
    if (row >= nrows) return;   // wave-uniform guard

    const vf4* __restrict__ in4  = (const vf4*)(adj + (size_t)row * NCOL);
    vf4* __restrict__       out4 = (vf4*)(out + (size_t)row * NCOL);

    // Load 64 elems/lane (coalesced 16B/lane), map to order-preserving uint
    // space (pos -> bits|0x80000000, neg -> ~bits), split into two 32-elem
    // halves for the 32x32 transposes.
    unsigned ulo[32], uhi[32];
#pragma unroll
    for (int c = 0; c < 16; ++c) {
        const vf4 v = __builtin_nontemporal_load(in4 + lane + 64 * c);
#pragma unroll
        for (int j = 0; j < 4; ++j) {
            const unsigned b = __float_as_uint(v[j]);
            const unsigned m = b ^ ((unsigned)((int)b >> 31) | 0x80000000u);
            const int e = 4 * c + j;
            if (e < 32) ulo[e] = m; else uhi[e - 32] = m;
        }
    }

    // values -> bit-planes
    transpose32(ulo);
    transpose32(uhi);

    // MSB-first radix bisection, plane p = bit (31-p).
    // Invariant: active = elements whose decided-bit prefix == cand's prefix;
    // need = rank of target within {active ∪ already-above}.
    unsigned alo = ~0u, ahi = ~0u;
    unsigned cand = 0u, need = KSEL;
#pragma unroll
    for (int p = 0; p < 32; ++p) {
        const unsigned bit = 1u << (31 - p);
        const unsigned cl = ulo[p] & alo;
        const unsigned ch = uhi[p] & ahi;
        const unsigned C = wave_sum((unsigned)__popc(cl) + (unsigned)__popc(ch));
        const bool take = (C >= need);        // uniform (readlane) -> SALU
        const unsigned msel = take ? 0u : ~0u;
        alo &= ulo[p] ^ msel;                 // take: &plane ; else: &~plane
        ahi &= uhi[p] ^ msel;
        cand |= take ? bit : 0u;
        need -= take ? 0u : C;
    }

    // bit-planes -> values (transpose is an involution)
    transpose32(ulo);
    transpose32(uhi);

    // Select in u-space (total order; ±0 mismatches vs float '>=' still emit
    // a zero value -> identical output), inverse map to original float bits.
#pragma unroll
    for (int c = 0; c < 16; ++c) {
        vf4 o;
#pragma unroll
        for (int j = 0; j < 4; ++j) {
            const int e = 4 * c + j;
            const unsigned uu = (e < 32) ? ulo[e] : uhi[e - 32];
            const unsigned inv = (unsigned)((int)(~uu) >> 31) | 0x80000000u;
            const float f = __uint_as_float(uu ^ inv);   // bit-exact original
            o[j] = (uu >= cand) ? f : 0.0f;
        }
        __builtin_nontemporal_store(o, out4 + lane + 64 * c);
    }
}

extern "C" void kernel_launch(void* const* d_in, const int* in_sizes, int n_in,
                              void* d_out, int out_size, void* d_ws, size_t ws_size,
                              hipStream_t stream) {
    const float* adj = (const float*)d_in[0];
    float* out = (float*)d_out;
    const int rows = in_sizes[0] / NCOL;       // 8 * 4096 = 32768
    const int blocks = (rows + 3) / 4;         // 4 waves (rows) per 256-thread block
    sparsify_kernel<<<blocks, 256, 0, stream>>>(adj, out, rows);
}